// Round 13
// baseline (299.898 us; speedup 1.0000x reference)
//
#include <hip/hip_runtime.h>
#include <math.h>

#define N_NODES 50000
#define N_EDGES 1600000
#define C 64
#define OUTC 7

#define NB 196         // coarse buckets: dst >> 8  (49999>>8 = 195)
#define BCAP 10240     // bucket capacity (mean 8192, sigma ~90)
#define CHUNK 4096     // edges per phase-1 workgroup
#define HROW 16        // u32 per half-table row (32 bf16 channels)

// fp32 -> bf16 (RNE), packed pair into u32 (lo = even channel, hi = odd)
__device__ __forceinline__ unsigned int pk_bf16(float a, float b) {
    unsigned int ua = __float_as_uint(a);
    ua = (ua + 0x7FFFu + ((ua >> 16) & 1u)) >> 16;
    unsigned int ub = __float_as_uint(b);
    ub = (ub + 0x7FFFu + ((ub >> 16) & 1u)) >> 16;
    return ua | (ub << 16);
}

// ---------------- CSR build, phase 1: coarse binning ----------------
// Pack edge as (dst<<16)|src (both < 65536). bucket = v >> 24 (= dst>>8).
__global__ __launch_bounds__(256) void bin_kernel(const int* __restrict__ src,
                                                  const int* __restrict__ dst,
                                                  unsigned int* __restrict__ buckets,
                                                  int* __restrict__ gcursor) {
    __shared__ unsigned int staged[CHUNK];          // 16 KB
    __shared__ int hist[NB], scanb[NB], cur[NB], baseb[NB];
    const int tid = threadIdx.x;
    const int base = blockIdx.x * CHUNK;
    int n = N_EDGES - base; if (n > CHUNK) n = CHUNK;  // multiple of 4

    for (int b = tid; b < NB; b += 256) { hist[b] = 0; cur[b] = 0; }
    __syncthreads();

    const int4* src4 = (const int4*)(src + base);
    const int4* dst4 = (const int4*)(dst + base);
    unsigned int v[16];
    int nv = n >> 2;
#pragma unroll
    for (int k = 0; k < 4; ++k) {
        int i4 = k * 256 + tid;
        if (i4 < nv) {
            int4 s4 = src4[i4];
            int4 d4 = dst4[i4];
            unsigned int d0 = (unsigned int)d4.x, d1 = (unsigned int)d4.y;
            unsigned int d2 = (unsigned int)d4.z, d3 = (unsigned int)d4.w;
            v[k * 4 + 0] = (d0 << 16) | (unsigned int)s4.x;
            v[k * 4 + 1] = (d1 << 16) | (unsigned int)s4.y;
            v[k * 4 + 2] = (d2 << 16) | (unsigned int)s4.z;
            v[k * 4 + 3] = (d3 << 16) | (unsigned int)s4.w;
            atomicAdd(&hist[d0 >> 8], 1);
            atomicAdd(&hist[d1 >> 8], 1);
            atomicAdd(&hist[d2 >> 8], 1);
            atomicAdd(&hist[d3 >> 8], 1);
        }
    }
    __syncthreads();
    if (tid == 0) {
        int run = 0;
        for (int b = 0; b < NB; ++b) { scanb[b] = run; run += hist[b]; }
    }
    __syncthreads();
#pragma unroll
    for (int k = 0; k < 4; ++k) {
        int i4 = k * 256 + tid;
        if (i4 < nv) {
#pragma unroll
            for (int q = 0; q < 4; ++q) {
                unsigned int w = v[k * 4 + q];
                int b = w >> 24;
                int p = scanb[b] + atomicAdd(&cur[b], 1);
                staged[p] = w;
            }
        }
    }
    __syncthreads();
    if (tid < NB) baseb[tid] = atomicAdd(&gcursor[tid], hist[tid]);
    __syncthreads();
    for (int i = tid; i < n; i += 256) {
        unsigned int w = staged[i];
        int b = w >> 24;
        buckets[(size_t)b * BCAP + baseb[b] + (i - scanb[b])] = w;
    }
}

// ---------------- CSR build, phase 2: per-bucket local CSR ----------------
__global__ __launch_bounds__(256) void build_csr(const unsigned int* __restrict__ buckets,
                                                 const int* __restrict__ gcursor,
                                                 unsigned int* __restrict__ csr,
                                                 int* __restrict__ off) {
    __shared__ int hist[256], part[256], offx[256], cur[256];
    __shared__ int gl[NB];
    __shared__ int s_cnt, s_base;
    const int tid = threadIdx.x;
    const int b = blockIdx.x;

    hist[tid] = 0;
    cur[tid] = 0;
    if (tid < NB) gl[tid] = gcursor[tid];
    __syncthreads();
    if (tid == 0) {
        int bs = 0;
        for (int i = 0; i < b; ++i) bs += gl[i];
        s_base = bs;
        s_cnt = gl[b];
    }
    __syncthreads();
    const int cnt = s_cnt;
    const int gbase = s_base;
    const unsigned int* bk = buckets + (size_t)b * BCAP;

    for (int i = tid; i < cnt; i += 256) {
        atomicAdd(&hist[(bk[i] >> 16) & 255], 1);
    }
    __syncthreads();
    part[tid] = hist[tid];
    __syncthreads();
    for (int d = 1; d < 256; d <<= 1) {
        int t = (tid >= d) ? part[tid - d] : 0;
        __syncthreads();
        part[tid] += t;
        __syncthreads();
    }
    offx[tid] = (tid == 0) ? 0 : part[tid - 1];
    __syncthreads();
    int node = b * 256 + tid;
    if (node < N_NODES) off[node] = gbase + offx[tid];
    if (b == NB - 1 && tid == 0) off[N_NODES] = gbase + cnt;
    for (int i = tid; i < cnt; i += 256) {
        unsigned int w = bk[i];
        int dl = (w >> 16) & 255;
        int p = offx[dl] + atomicAdd(&cur[dl], 1);
        csr[gbase + p] = w & 0xFFFFu;
    }
}

// ---------------- dense linears ----------------

// Block-level channel-group split: cg = blockIdx.x & 3 (SGPR-native).
// Output goes into TWO contiguous half-tables (32 ch each, 64 B rows):
// half = cg>>1, within-half u32 offset = (cg&1)*8. Each half = 3.2 MB ->
// fits a 4 MB per-XCD L2 during the gather's temporal half-passes.
__global__ __launch_bounds__(256) void linear64_bf16(const float* __restrict__ x,
                                                     const float* __restrict__ W,
                                                     unsigned int* __restrict__ tb) {
    const int cg = blockIdx.x & 3;
    const int r = (blockIdx.x >> 2) * 256 + threadIdx.x;
    if (r >= N_NODES) return;
    float4 xr[16];
    const float4* xp = (const float4*)(x + (size_t)r * 64);
#pragma unroll
    for (int j = 0; j < 16; ++j) xr[j] = xp[j];
    const float* xf = (const float*)xr;

    const float* Wp = W + cg * 16 * 64;   // uniform GEP -> s_load
    unsigned int* orow = tb + (size_t)(cg >> 1) * N_NODES * HROW
                            + (size_t)r * HROW + (cg & 1) * 8;
    for (int c0 = 0; c0 < 16; c0 += 8) {
        float acc[8] = {0.f, 0.f, 0.f, 0.f, 0.f, 0.f, 0.f, 0.f};
#pragma unroll
        for (int k = 0; k < 64; ++k) {
            float xv = xf[k];
#pragma unroll
            for (int j = 0; j < 8; ++j)
                acc[j] += xv * Wp[(c0 + j) * 64 + k];  // uniform -> s_load
        }
        uint4 w;
        w.x = pk_bf16(acc[0], acc[1]);
        w.y = pk_bf16(acc[2], acc[3]);
        w.z = pk_bf16(acc[4], acc[5]);
        w.w = pk_bf16(acc[6], acc[7]);
        ((uint4*)orow)[c0 >> 3] = w;
    }
}

// Thread-per-row, fully-uniform W3 (kernel arg) -> auto-scalarized s_loads.
__global__ __launch_bounds__(128) void linear7_rows(const float* __restrict__ x,
                                                    const float* __restrict__ W,
                                                    float* __restrict__ out) {
    int r = blockIdx.x * 128 + threadIdx.x;
    if (r >= N_NODES) return;
    float4 xr[16];
    const float4* xp = (const float4*)(x + (size_t)r * 64);
#pragma unroll
    for (int j = 0; j < 16; ++j) xr[j] = xp[j];
    const float* xf = (const float*)xr;

    float acc[7] = {0.f, 0.f, 0.f, 0.f, 0.f, 0.f, 0.f};
#pragma unroll
    for (int k = 0; k < 64; ++k) {
        float xv = xf[k];
#pragma unroll
        for (int j = 0; j < 7; ++j)
            acc[j] += xv * W[j * 64 + k];  // uniform -> s_load
    }
    float4* op = (float4*)(out + (size_t)r * 8);
    op[0] = make_float4(acc[0], acc[1], acc[2], acc[3]);
    op[1] = make_float4(acc[4], acc[5], acc[6], 0.f);
}

// ---------------- gather: bf16 half-table (3.2 MB, L2-resident) ------------

// One temporal pass over half h: table slice = tb + h*N_NODES*HROW, 64 B rows.
// Lane map: slot = lane>>2 (16 edge slots), ch4 = lane&3 (uint4 = 8 bf16 ch).
// One wave-instr covers 16 edge rows; avg degree 32 -> 2 iterations.
__global__ __launch_bounds__(256) void gather_half(const int* __restrict__ off,
                                                   const unsigned int* __restrict__ csr_src,
                                                   const unsigned int* __restrict__ tb,
                                                   const float* __restrict__ b,
                                                   float* __restrict__ out,
                                                   int h, int do_relu) {
    int node = blockIdx.x * 4 + (threadIdx.x >> 6);
    if (node >= N_NODES) return;
    const int lane = threadIdx.x & 63;
    const int slot = lane >> 2;
    const int ch4  = lane & 3;
    int e0 = off[node], e1 = off[node + 1];
    const uint4* t4 = (const uint4*)(tb + (size_t)h * N_NODES * HROW);
    float s[8] = {0.f, 0.f, 0.f, 0.f, 0.f, 0.f, 0.f, 0.f};
    for (int e = e0; e < e1; e += 16) {
        int i = e + slot;
        bool p = i < e1;
        unsigned int a = csr_src[p ? i : e];
        uint4 v = t4[(size_t)a * 4 + ch4];
        if (p) {
            s[0] += __uint_as_float(v.x << 16);
            s[1] += __uint_as_float(v.x & 0xFFFF0000u);
            s[2] += __uint_as_float(v.y << 16);
            s[3] += __uint_as_float(v.y & 0xFFFF0000u);
            s[4] += __uint_as_float(v.z << 16);
            s[5] += __uint_as_float(v.z & 0xFFFF0000u);
            s[6] += __uint_as_float(v.w << 16);
            s[7] += __uint_as_float(v.w & 0xFFFF0000u);
        }
    }
    // fold 16 slots (lane bits 2..5); ch4 bits preserved
#pragma unroll
    for (int d = 4; d <= 32; d <<= 1) {
#pragma unroll
        for (int j = 0; j < 8; ++j) s[j] += __shfl_xor(s[j], d, 64);
    }
    if (lane < 4) {
        const float* bh = b + h * 32;
        const float4 b0 = ((const float4*)bh)[ch4 * 2];
        const float4 b1 = ((const float4*)bh)[ch4 * 2 + 1];
        float4 r0, r1;
        r0.x = s[0] + b0.x; r0.y = s[1] + b0.y; r0.z = s[2] + b0.z; r0.w = s[3] + b0.w;
        r1.x = s[4] + b1.x; r1.y = s[5] + b1.y; r1.z = s[6] + b1.z; r1.w = s[7] + b1.w;
        if (do_relu) {
            r0.x = fmaxf(r0.x, 0.f); r0.y = fmaxf(r0.y, 0.f);
            r0.z = fmaxf(r0.z, 0.f); r0.w = fmaxf(r0.w, 0.f);
            r1.x = fmaxf(r1.x, 0.f); r1.y = fmaxf(r1.y, 0.f);
            r1.z = fmaxf(r1.z, 0.f); r1.w = fmaxf(r1.w, 0.f);
        }
        float4* orow = (float4*)(out + (size_t)node * 64 + h * 32 + ch4 * 8);
        orow[0] = r0;
        orow[1] = r1;
    }
}

// 7-ch gather + bias + log_softmax (fp32 t3, 1.6 MB -> already L2-resident).
__global__ __launch_bounds__(256) void gather7_lsm(const int* __restrict__ off,
                                                   const unsigned int* __restrict__ csr_src,
                                                   const float* __restrict__ t3,
                                                   const float* __restrict__ b,
                                                   float* __restrict__ out) {
    int node = blockIdx.x * 4 + (threadIdx.x >> 6);
    if (node >= N_NODES) return;
    const int lane = threadIdx.x & 63;
    const int slot = lane >> 1;
    const int h    = lane & 1;
    int e0 = off[node], e1 = off[node + 1];
    const float4* t4 = (const float4*)t3;
    float sx = 0.f, sy = 0.f, sz = 0.f, sw = 0.f;
    for (int e = e0 + slot; e < e1; e += 32) {
        unsigned int s = csr_src[e];
        float4 v = t4[(size_t)s * 2 + h];
        sx += v.x; sy += v.y; sz += v.z; sw += v.w;
    }
#pragma unroll
    for (int d = 2; d <= 32; d <<= 1) {
        sx += __shfl_xor(sx, d, 64); sy += __shfl_xor(sy, d, 64);
        sz += __shfl_xor(sz, d, 64); sw += __shfl_xor(sw, d, 64);
    }
    float z0 = sx + b[h * 4 + 0];
    float z1 = sy + b[h * 4 + 1];
    float z2 = sz + b[h * 4 + 2];
    float z3 = (h == 0) ? (sw + b[3]) : -1e30f;
    float m = fmaxf(fmaxf(z0, z1), fmaxf(z2, z3));
    m = fmaxf(m, __shfl_xor(m, 1, 64));
    float ex = __expf(z0 - m) + __expf(z1 - m) + __expf(z2 - m) + __expf(z3 - m);
    ex += __shfl_xor(ex, 1, 64);
    float l = m + __logf(ex);
    if (lane < 2) {
        float* o = out + (size_t)node * 7 + h * 4;
        o[0] = z0 - l; o[1] = z1 - l; o[2] = z2 - l;
        if (h == 0) o[3] = z3 - l;
    }
}

extern "C" void kernel_launch(void* const* d_in, const int* in_sizes, int n_in,
                              void* d_out, int out_size, void* d_ws, size_t ws_size,
                              hipStream_t stream) {
    const float* x  = (const float*)d_in[0];
    const int*   ei = (const int*)d_in[1];
    const float* W1 = (const float*)d_in[2];
    const float* b1 = (const float*)d_in[3];
    const float* W2 = (const float*)d_in[4];
    const float* b2 = (const float*)d_in[5];
    const float* W3 = (const float*)d_in[6];
    const float* b3 = (const float*)d_in[7];
    float* out = (float*)d_out;

    const int* src = ei;
    const int* dst = ei + N_EDGES;

    // workspace: A region (12.8 MB): phase-1 buckets (8.03 MB, dead after
    // build_csr) -> two bf16 half-tables (2 x 3.2 MB) -> fp32 stride-8 t3.
    float* A = (float*)d_ws;                       // 12.8 MB
    float* B = A + (size_t)N_NODES * C;            // 12.8 MB (fp32 h buffer)
    unsigned int* csr = (unsigned int*)(B + (size_t)N_NODES * C);
    int* off     = (int*)(csr + N_EDGES);          // 50001
    int* gcursor = off + N_NODES + 8;              // 196
    unsigned int* buckets = (unsigned int*)A;      // aliases A
    unsigned int* Abf     = (unsigned int*)A;      // half-table pair view

    const int l64grid = ((N_NODES + 255) / 256) * 4;  // 196 rowgroups x 4 cgs
    const int l7grid  = (N_NODES + 127) / 128;        // 391
    const int ngrid   = (N_NODES + 3) / 4;            // 12500

    // ---- CSR build
    (void)hipMemsetAsync(gcursor, 0, NB * sizeof(int), stream);
    bin_kernel<<<(N_EDGES + CHUNK - 1) / CHUNK, 256, 0, stream>>>(src, dst, buckets, gcursor);
    build_csr<<<NB, 256, 0, stream>>>(buckets, gcursor, csr, off);

    // ---- layer 1 (A free after build_csr); gather = 2 temporal half-passes
    linear64_bf16<<<l64grid, 256, 0, stream>>>(x, W1, Abf);
    gather_half<<<ngrid, 256, 0, stream>>>(off, csr, Abf, b1, B, 0, 1);
    gather_half<<<ngrid, 256, 0, stream>>>(off, csr, Abf, b1, B, 1, 1);

    // ---- layer 2
    linear64_bf16<<<l64grid, 256, 0, stream>>>(B, W2, Abf);
    gather_half<<<ngrid, 256, 0, stream>>>(off, csr, Abf, b2, B, 0, 1);
    gather_half<<<ngrid, 256, 0, stream>>>(off, csr, Abf, b2, B, 1, 1);

    // ---- layer 3 (fp32 staging, stride-8)
    linear7_rows<<<l7grid, 128, 0, stream>>>(B, W3, A);
    gather7_lsm<<<ngrid, 256, 0, stream>>>(off, csr, A, b3, out);
}

// Round 14
// 275.855 us; speedup vs baseline: 1.0872x; 1.0872x over previous
//
#include <hip/hip_runtime.h>
#include <math.h>

#define N_NODES 50000
#define N_EDGES 1600000
#define C 64
#define OUTC 7

#define NB 196         // coarse buckets: dst >> 8  (49999>>8 = 195)
#define BCAP 10240     // bucket capacity (mean 8192, sigma ~90)
#define CHUNK 4096     // edges per phase-1 workgroup

typedef float nfloat4 __attribute__((ext_vector_type(4)));  // nt-store-compatible

// fp32 -> bf16 (RNE), packed pair into u32 (lo = even channel, hi = odd)
__device__ __forceinline__ unsigned int pk_bf16(float a, float b) {
    unsigned int ua = __float_as_uint(a);
    ua = (ua + 0x7FFFu + ((ua >> 16) & 1u)) >> 16;
    unsigned int ub = __float_as_uint(b);
    ub = (ub + 0x7FFFu + ((ub >> 16) & 1u)) >> 16;
    return ua | (ub << 16);
}

// ---------------- CSR build, phase 1: coarse binning ----------------
// Pack edge as (dst<<16)|src (both < 65536). bucket = v >> 24 (= dst>>8).
__global__ __launch_bounds__(256) void bin_kernel(const int* __restrict__ src,
                                                  const int* __restrict__ dst,
                                                  unsigned int* __restrict__ buckets,
                                                  int* __restrict__ gcursor) {
    __shared__ unsigned int staged[CHUNK];          // 16 KB
    __shared__ int hist[NB], scanb[NB], cur[NB], baseb[NB];
    const int tid = threadIdx.x;
    const int base = blockIdx.x * CHUNK;
    int n = N_EDGES - base; if (n > CHUNK) n = CHUNK;  // multiple of 4

    for (int b = tid; b < NB; b += 256) { hist[b] = 0; cur[b] = 0; }
    __syncthreads();

    const int4* src4 = (const int4*)(src + base);
    const int4* dst4 = (const int4*)(dst + base);
    unsigned int v[16];
    int nv = n >> 2;
#pragma unroll
    for (int k = 0; k < 4; ++k) {
        int i4 = k * 256 + tid;
        if (i4 < nv) {
            int4 s4 = src4[i4];
            int4 d4 = dst4[i4];
            unsigned int d0 = (unsigned int)d4.x, d1 = (unsigned int)d4.y;
            unsigned int d2 = (unsigned int)d4.z, d3 = (unsigned int)d4.w;
            v[k * 4 + 0] = (d0 << 16) | (unsigned int)s4.x;
            v[k * 4 + 1] = (d1 << 16) | (unsigned int)s4.y;
            v[k * 4 + 2] = (d2 << 16) | (unsigned int)s4.z;
            v[k * 4 + 3] = (d3 << 16) | (unsigned int)s4.w;
            atomicAdd(&hist[d0 >> 8], 1);
            atomicAdd(&hist[d1 >> 8], 1);
            atomicAdd(&hist[d2 >> 8], 1);
            atomicAdd(&hist[d3 >> 8], 1);
        }
    }
    __syncthreads();
    if (tid == 0) {
        int run = 0;
        for (int b = 0; b < NB; ++b) { scanb[b] = run; run += hist[b]; }
    }
    __syncthreads();
#pragma unroll
    for (int k = 0; k < 4; ++k) {
        int i4 = k * 256 + tid;
        if (i4 < nv) {
#pragma unroll
            for (int q = 0; q < 4; ++q) {
                unsigned int w = v[k * 4 + q];
                int b = w >> 24;
                int p = scanb[b] + atomicAdd(&cur[b], 1);
                staged[p] = w;
            }
        }
    }
    __syncthreads();
    if (tid < NB) baseb[tid] = atomicAdd(&gcursor[tid], hist[tid]);
    __syncthreads();
    for (int i = tid; i < n; i += 256) {
        unsigned int w = staged[i];
        int b = w >> 24;
        buckets[(size_t)b * BCAP + baseb[b] + (i - scanb[b])] = w;
    }
}

// ---------------- CSR build, phase 2: per-bucket local CSR (u16 out) --------
__global__ __launch_bounds__(256) void build_csr(const unsigned int* __restrict__ buckets,
                                                 const int* __restrict__ gcursor,
                                                 unsigned short* __restrict__ csr,
                                                 int* __restrict__ off) {
    __shared__ int hist[256], part[256], offx[256], cur[256];
    __shared__ int gl[NB];
    __shared__ int s_cnt, s_base;
    const int tid = threadIdx.x;
    const int b = blockIdx.x;

    hist[tid] = 0;
    cur[tid] = 0;
    if (tid < NB) gl[tid] = gcursor[tid];
    __syncthreads();
    if (tid == 0) {
        int bs = 0;
        for (int i = 0; i < b; ++i) bs += gl[i];
        s_base = bs;
        s_cnt = gl[b];
    }
    __syncthreads();
    const int cnt = s_cnt;
    const int gbase = s_base;
    const unsigned int* bk = buckets + (size_t)b * BCAP;

    for (int i = tid; i < cnt; i += 256) {
        atomicAdd(&hist[(bk[i] >> 16) & 255], 1);
    }
    __syncthreads();
    part[tid] = hist[tid];
    __syncthreads();
    for (int d = 1; d < 256; d <<= 1) {
        int t = (tid >= d) ? part[tid - d] : 0;
        __syncthreads();
        part[tid] += t;
        __syncthreads();
    }
    offx[tid] = (tid == 0) ? 0 : part[tid - 1];
    __syncthreads();
    int node = b * 256 + tid;
    if (node < N_NODES) off[node] = gbase + offx[tid];
    if (b == NB - 1 && tid == 0) off[N_NODES] = gbase + cnt;
    for (int i = tid; i < cnt; i += 256) {
        unsigned int w = bk[i];
        int dl = (w >> 16) & 255;
        int p = offx[dl] + atomicAdd(&cur[dl], 1);
        csr[gbase + p] = (unsigned short)(w & 0xFFFFu);
    }
}

// ---------------- dense linears ----------------

// Block-level channel-group split: cg = blockIdx.x & 3 (SGPR-native,
// workgroup-uniform) owns channels [cg*16, cg*16+16); thread = row.
// W + cg*1024 is a plain GEP on the __restrict__ arg -> s_load (K$).
__global__ __launch_bounds__(256) void linear64_bf16(const float* __restrict__ x,
                                                     const float* __restrict__ W,
                                                     unsigned int* __restrict__ tb) {
    const int cg = blockIdx.x & 3;
    const int r = (blockIdx.x >> 2) * 256 + threadIdx.x;
    if (r >= N_NODES) return;
    float4 xr[16];
    const float4* xp = (const float4*)(x + (size_t)r * 64);
#pragma unroll
    for (int j = 0; j < 16; ++j) xr[j] = xp[j];
    const float* xf = (const float*)xr;

    const float* Wp = W + cg * 16 * 64;   // uniform GEP -> s_load
    unsigned int* orow = tb + (size_t)r * 32 + cg * 8;  // 8 u32 = 16 bf16
    for (int c0 = 0; c0 < 16; c0 += 8) {
        float acc[8] = {0.f, 0.f, 0.f, 0.f, 0.f, 0.f, 0.f, 0.f};
#pragma unroll
        for (int k = 0; k < 64; ++k) {
            float xv = xf[k];
#pragma unroll
            for (int j = 0; j < 8; ++j)
                acc[j] += xv * Wp[(c0 + j) * 64 + k];  // uniform -> s_load
        }
        uint4 w;
        w.x = pk_bf16(acc[0], acc[1]);
        w.y = pk_bf16(acc[2], acc[3]);
        w.z = pk_bf16(acc[4], acc[5]);
        w.w = pk_bf16(acc[6], acc[7]);
        ((uint4*)orow)[c0 >> 3] = w;
    }
}

// Thread-per-row, fully-uniform W3 (kernel arg) -> auto-scalarized s_loads.
__global__ __launch_bounds__(128) void linear7_rows(const float* __restrict__ x,
                                                    const float* __restrict__ W,
                                                    float* __restrict__ out) {
    int r = blockIdx.x * 128 + threadIdx.x;
    if (r >= N_NODES) return;
    float4 xr[16];
    const float4* xp = (const float4*)(x + (size_t)r * 64);
#pragma unroll
    for (int j = 0; j < 16; ++j) xr[j] = xp[j];
    const float* xf = (const float*)xr;

    float acc[7] = {0.f, 0.f, 0.f, 0.f, 0.f, 0.f, 0.f};
#pragma unroll
    for (int k = 0; k < 64; ++k) {
        float xv = xf[k];
#pragma unroll
        for (int j = 0; j < 7; ++j)
            acc[j] += xv * W[j * 64 + k];  // uniform -> s_load
    }
    float4* op = (float4*)(out + (size_t)r * 8);
    op[0] = make_float4(acc[0], acc[1], acc[2], acc[3]);
    op[1] = make_float4(acc[4], acc[5], acc[6], 0.f);
}

// ---------------- gather aggregation: bf16 table, fp32 accumulate ----------

// Lane map: slot = lane>>3 (8 edge slots), ch8 = lane&7 (uint4 = 8 bf16 ch).
// csr: nt load (streamed once); out: nt store (streamed once) -> neither
// pollutes the per-XCD L2, leaving it for the 6.4 MB bf16 table.
__global__ __launch_bounds__(256) void gather64b(const int* __restrict__ off,
                                                 const unsigned short* __restrict__ csr_src,
                                                 const unsigned int* __restrict__ tb,
                                                 const float* __restrict__ b,
                                                 float* __restrict__ out,
                                                 int do_relu) {
    int node = blockIdx.x * 4 + (threadIdx.x >> 6);
    if (node >= N_NODES) return;
    const int lane = threadIdx.x & 63;
    const int slot = lane >> 3;
    const int ch8  = lane & 7;
    int e0 = off[node], e1 = off[node + 1];
    const uint4* t4 = (const uint4*)tb;
    float s[8] = {0.f, 0.f, 0.f, 0.f, 0.f, 0.f, 0.f, 0.f};
    for (int e = e0; e < e1; e += 16) {
        int i0 = e + slot;
        int i1 = e + 8 + slot;
        bool p0 = i0 < e1, p1 = i1 < e1;
        unsigned int a0 = __builtin_nontemporal_load(csr_src + (p0 ? i0 : e));
        unsigned int a1 = __builtin_nontemporal_load(csr_src + (p1 ? i1 : e));
        uint4 v0 = t4[(size_t)a0 * 8 + ch8];
        uint4 v1 = t4[(size_t)a1 * 8 + ch8];
        if (p0) {
            s[0] += __uint_as_float(v0.x << 16);
            s[1] += __uint_as_float(v0.x & 0xFFFF0000u);
            s[2] += __uint_as_float(v0.y << 16);
            s[3] += __uint_as_float(v0.y & 0xFFFF0000u);
            s[4] += __uint_as_float(v0.z << 16);
            s[5] += __uint_as_float(v0.z & 0xFFFF0000u);
            s[6] += __uint_as_float(v0.w << 16);
            s[7] += __uint_as_float(v0.w & 0xFFFF0000u);
        }
        if (p1) {
            s[0] += __uint_as_float(v1.x << 16);
            s[1] += __uint_as_float(v1.x & 0xFFFF0000u);
            s[2] += __uint_as_float(v1.y << 16);
            s[3] += __uint_as_float(v1.y & 0xFFFF0000u);
            s[4] += __uint_as_float(v1.z << 16);
            s[5] += __uint_as_float(v1.z & 0xFFFF0000u);
            s[6] += __uint_as_float(v1.w << 16);
            s[7] += __uint_as_float(v1.w & 0xFFFF0000u);
        }
    }
#pragma unroll
    for (int d = 8; d <= 32; d <<= 1) {
#pragma unroll
        for (int j = 0; j < 8; ++j) s[j] += __shfl_xor(s[j], d, 64);
    }
    if (lane < 8) {
        const float4 b0 = ((const float4*)b)[ch8 * 2];
        const float4 b1 = ((const float4*)b)[ch8 * 2 + 1];
        nfloat4 r0, r1;
        r0.x = s[0] + b0.x; r0.y = s[1] + b0.y; r0.z = s[2] + b0.z; r0.w = s[3] + b0.w;
        r1.x = s[4] + b1.x; r1.y = s[5] + b1.y; r1.z = s[6] + b1.z; r1.w = s[7] + b1.w;
        if (do_relu) {
            r0.x = fmaxf(r0.x, 0.f); r0.y = fmaxf(r0.y, 0.f);
            r0.z = fmaxf(r0.z, 0.f); r0.w = fmaxf(r0.w, 0.f);
            r1.x = fmaxf(r1.x, 0.f); r1.y = fmaxf(r1.y, 0.f);
            r1.z = fmaxf(r1.z, 0.f); r1.w = fmaxf(r1.w, 0.f);
        }
        nfloat4* orow = (nfloat4*)(out + (size_t)node * 64 + ch8 * 8);
        __builtin_nontemporal_store(r0, orow);
        __builtin_nontemporal_store(r1, orow + 1);
    }
}

// 7-ch gather + bias + log_softmax (fp32 t3). slot = lane>>1, h = lane&1.
__global__ __launch_bounds__(256) void gather7_lsm(const int* __restrict__ off,
                                                   const unsigned short* __restrict__ csr_src,
                                                   const float* __restrict__ t3,
                                                   const float* __restrict__ b,
                                                   float* __restrict__ out) {
    int node = blockIdx.x * 4 + (threadIdx.x >> 6);
    if (node >= N_NODES) return;
    const int lane = threadIdx.x & 63;
    const int slot = lane >> 1;
    const int h    = lane & 1;
    int e0 = off[node], e1 = off[node + 1];
    const float4* t4 = (const float4*)t3;
    float sx = 0.f, sy = 0.f, sz = 0.f, sw = 0.f;
    for (int e = e0 + slot; e < e1; e += 32) {
        unsigned int s = __builtin_nontemporal_load(csr_src + e);
        float4 v = t4[(size_t)s * 2 + h];
        sx += v.x; sy += v.y; sz += v.z; sw += v.w;
    }
#pragma unroll
    for (int d = 2; d <= 32; d <<= 1) {
        sx += __shfl_xor(sx, d, 64); sy += __shfl_xor(sy, d, 64);
        sz += __shfl_xor(sz, d, 64); sw += __shfl_xor(sw, d, 64);
    }
    float z0 = sx + b[h * 4 + 0];
    float z1 = sy + b[h * 4 + 1];
    float z2 = sz + b[h * 4 + 2];
    float z3 = (h == 0) ? (sw + b[3]) : -1e30f;
    float m = fmaxf(fmaxf(z0, z1), fmaxf(z2, z3));
    m = fmaxf(m, __shfl_xor(m, 1, 64));
    float ex = __expf(z0 - m) + __expf(z1 - m) + __expf(z2 - m) + __expf(z3 - m);
    ex += __shfl_xor(ex, 1, 64);
    float l = m + __logf(ex);
    if (lane < 2) {
        float* o = out + (size_t)node * 7 + h * 4;
        o[0] = z0 - l; o[1] = z1 - l; o[2] = z2 - l;
        if (h == 0) o[3] = z3 - l;
    }
}

extern "C" void kernel_launch(void* const* d_in, const int* in_sizes, int n_in,
                              void* d_out, int out_size, void* d_ws, size_t ws_size,
                              hipStream_t stream) {
    const float* x  = (const float*)d_in[0];
    const int*   ei = (const int*)d_in[1];
    const float* W1 = (const float*)d_in[2];
    const float* b1 = (const float*)d_in[3];
    const float* W2 = (const float*)d_in[4];
    const float* b2 = (const float*)d_in[5];
    const float* W3 = (const float*)d_in[6];
    const float* b3 = (const float*)d_in[7];
    float* out = (float*)d_out;

    const int* src = ei;
    const int* dst = ei + N_EDGES;

    // workspace: A region (12.8 MB): phase-1 buckets (8.03 MB, dead after
    // build_csr) -> bf16 table (6.4 MB, layers 1-2) -> fp32 stride-8 t3.
    float* A = (float*)d_ws;                       // 12.8 MB
    float* B = A + (size_t)N_NODES * C;            // 12.8 MB (fp32 h buffer)
    unsigned short* csr = (unsigned short*)(B + (size_t)N_NODES * C);  // 3.2 MB
    int* off     = (int*)(csr + N_EDGES);          // 50001
    int* gcursor = off + N_NODES + 8;              // 196
    unsigned int* buckets = (unsigned int*)A;      // aliases A
    unsigned int* Abf     = (unsigned int*)A;      // bf16 table view

    const int l64grid = ((N_NODES + 255) / 256) * 4;  // 196 rowgroups x 4 cgs
    const int l7grid  = (N_NODES + 127) / 128;        // 391
    const int ngrid   = (N_NODES + 3) / 4;            // 12500

    // ---- CSR build
    (void)hipMemsetAsync(gcursor, 0, NB * sizeof(int), stream);
    bin_kernel<<<(N_EDGES + CHUNK - 1) / CHUNK, 256, 0, stream>>>(src, dst, buckets, gcursor);
    build_csr<<<NB, 256, 0, stream>>>(buckets, gcursor, csr, off);

    // ---- layer 1 (A free after build_csr)
    linear64_bf16<<<l64grid, 256, 0, stream>>>(x, W1, Abf);
    gather64b<<<ngrid, 256, 0, stream>>>(off, csr, Abf, b1, B, 1);

    // ---- layer 2
    linear64_bf16<<<l64grid, 256, 0, stream>>>(B, W2, Abf);
    gather64b<<<ngrid, 256, 0, stream>>>(off, csr, Abf, b2, B, 1);

    // ---- layer 3 (fp32 staging, stride-8)
    linear7_rows<<<l7grid, 128, 0, stream>>>(B, W3, A);
    gather7_lsm<<<ngrid, 256, 0, stream>>>(off, csr, A, b3, out);
}

// Round 15
// 274.764 us; speedup vs baseline: 1.0915x; 1.0040x over previous
//
#include <hip/hip_runtime.h>
#include <math.h>

#define N_NODES 50000
#define N_EDGES 1600000
#define C 64
#define OUTC 7

#define NB 196         // coarse buckets: dst >> 8  (49999>>8 = 195)
#define BCAP 10240     // bucket capacity (mean 8192, sigma ~90)
#define CHUNK 4096     // edges per phase-1 workgroup

// fp32 -> bf16 (RNE), packed pair into u32 (lo = even channel, hi = odd)
__device__ __forceinline__ unsigned int pk_bf16(float a, float b) {
    unsigned int ua = __float_as_uint(a);
    ua = (ua + 0x7FFFu + ((ua >> 16) & 1u)) >> 16;
    unsigned int ub = __float_as_uint(b);
    ub = (ub + 0x7FFFu + ((ub >> 16) & 1u)) >> 16;
    return ua | (ub << 16);
}

// ---------------- CSR build, phase 1: coarse binning ----------------
// Pack edge as (dst<<16)|src (both < 65536). bucket = v >> 24 (= dst>>8).
__global__ __launch_bounds__(256) void bin_kernel(const int* __restrict__ src,
                                                  const int* __restrict__ dst,
                                                  unsigned int* __restrict__ buckets,
                                                  int* __restrict__ gcursor) {
    __shared__ unsigned int staged[CHUNK];          // 16 KB
    __shared__ int hist[NB], scanb[NB], cur[NB], baseb[NB];
    const int tid = threadIdx.x;
    const int base = blockIdx.x * CHUNK;
    int n = N_EDGES - base; if (n > CHUNK) n = CHUNK;  // multiple of 4

    for (int b = tid; b < NB; b += 256) { hist[b] = 0; cur[b] = 0; }
    __syncthreads();

    const int4* src4 = (const int4*)(src + base);
    const int4* dst4 = (const int4*)(dst + base);
    unsigned int v[16];
    int nv = n >> 2;
#pragma unroll
    for (int k = 0; k < 4; ++k) {
        int i4 = k * 256 + tid;
        if (i4 < nv) {
            int4 s4 = src4[i4];
            int4 d4 = dst4[i4];
            unsigned int d0 = (unsigned int)d4.x, d1 = (unsigned int)d4.y;
            unsigned int d2 = (unsigned int)d4.z, d3 = (unsigned int)d4.w;
            v[k * 4 + 0] = (d0 << 16) | (unsigned int)s4.x;
            v[k * 4 + 1] = (d1 << 16) | (unsigned int)s4.y;
            v[k * 4 + 2] = (d2 << 16) | (unsigned int)s4.z;
            v[k * 4 + 3] = (d3 << 16) | (unsigned int)s4.w;
            atomicAdd(&hist[d0 >> 8], 1);
            atomicAdd(&hist[d1 >> 8], 1);
            atomicAdd(&hist[d2 >> 8], 1);
            atomicAdd(&hist[d3 >> 8], 1);
        }
    }
    __syncthreads();
    if (tid == 0) {
        int run = 0;
        for (int b = 0; b < NB; ++b) { scanb[b] = run; run += hist[b]; }
    }
    __syncthreads();
#pragma unroll
    for (int k = 0; k < 4; ++k) {
        int i4 = k * 256 + tid;
        if (i4 < nv) {
#pragma unroll
            for (int q = 0; q < 4; ++q) {
                unsigned int w = v[k * 4 + q];
                int b = w >> 24;
                int p = scanb[b] + atomicAdd(&cur[b], 1);
                staged[p] = w;
            }
        }
    }
    __syncthreads();
    if (tid < NB) baseb[tid] = atomicAdd(&gcursor[tid], hist[tid]);
    __syncthreads();
    for (int i = tid; i < n; i += 256) {
        unsigned int w = staged[i];
        int b = w >> 24;
        buckets[(size_t)b * BCAP + baseb[b] + (i - scanb[b])] = w;
    }
}

// ---------------- CSR build, phase 2: per-bucket local CSR (u16 out) --------
__global__ __launch_bounds__(256) void build_csr(const unsigned int* __restrict__ buckets,
                                                 const int* __restrict__ gcursor,
                                                 unsigned short* __restrict__ csr,
                                                 int* __restrict__ off) {
    __shared__ int hist[256], part[256], offx[256], cur[256];
    __shared__ int gl[NB];
    __shared__ int s_cnt, s_base;
    const int tid = threadIdx.x;
    const int b = blockIdx.x;

    hist[tid] = 0;
    cur[tid] = 0;
    if (tid < NB) gl[tid] = gcursor[tid];
    __syncthreads();
    if (tid == 0) {
        int bs = 0;
        for (int i = 0; i < b; ++i) bs += gl[i];
        s_base = bs;
        s_cnt = gl[b];
    }
    __syncthreads();
    const int cnt = s_cnt;
    const int gbase = s_base;
    const unsigned int* bk = buckets + (size_t)b * BCAP;

    for (int i = tid; i < cnt; i += 256) {
        atomicAdd(&hist[(bk[i] >> 16) & 255], 1);
    }
    __syncthreads();
    part[tid] = hist[tid];
    __syncthreads();
    for (int d = 1; d < 256; d <<= 1) {
        int t = (tid >= d) ? part[tid - d] : 0;
        __syncthreads();
        part[tid] += t;
        __syncthreads();
    }
    offx[tid] = (tid == 0) ? 0 : part[tid - 1];
    __syncthreads();
    int node = b * 256 + tid;
    if (node < N_NODES) off[node] = gbase + offx[tid];
    if (b == NB - 1 && tid == 0) off[N_NODES] = gbase + cnt;
    for (int i = tid; i < cnt; i += 256) {
        unsigned int w = bk[i];
        int dl = (w >> 16) & 255;
        int p = offx[dl] + atomicAdd(&cur[dl], 1);
        csr[gbase + p] = (unsigned short)(w & 0xFFFFu);
    }
}

// ---------------- dense linears ----------------

// Block-level channel-group split: cg = blockIdx.x & 3 (SGPR-native,
// workgroup-uniform) owns channels [cg*16, cg*16+16); thread = row.
// W + cg*1024 is a plain GEP on the __restrict__ arg -> s_load (K$).
__global__ __launch_bounds__(256) void linear64_bf16(const float* __restrict__ x,
                                                     const float* __restrict__ W,
                                                     unsigned int* __restrict__ tb) {
    const int cg = blockIdx.x & 3;
    const int r = (blockIdx.x >> 2) * 256 + threadIdx.x;
    if (r >= N_NODES) return;
    float4 xr[16];
    const float4* xp = (const float4*)(x + (size_t)r * 64);
#pragma unroll
    for (int j = 0; j < 16; ++j) xr[j] = xp[j];
    const float* xf = (const float*)xr;

    const float* Wp = W + cg * 16 * 64;   // uniform GEP -> s_load
    unsigned int* orow = tb + (size_t)r * 32 + cg * 8;  // 8 u32 = 16 bf16
    for (int c0 = 0; c0 < 16; c0 += 8) {
        float acc[8] = {0.f, 0.f, 0.f, 0.f, 0.f, 0.f, 0.f, 0.f};
#pragma unroll
        for (int k = 0; k < 64; ++k) {
            float xv = xf[k];
#pragma unroll
            for (int j = 0; j < 8; ++j)
                acc[j] += xv * Wp[(c0 + j) * 64 + k];  // uniform -> s_load
        }
        uint4 w;
        w.x = pk_bf16(acc[0], acc[1]);
        w.y = pk_bf16(acc[2], acc[3]);
        w.z = pk_bf16(acc[4], acc[5]);
        w.w = pk_bf16(acc[6], acc[7]);
        ((uint4*)orow)[c0 >> 3] = w;
    }
}

// Thread-per-row, fully-uniform W3 (kernel arg) -> auto-scalarized s_loads.
__global__ __launch_bounds__(128) void linear7_rows(const float* __restrict__ x,
                                                    const float* __restrict__ W,
                                                    float* __restrict__ out) {
    int r = blockIdx.x * 128 + threadIdx.x;
    if (r >= N_NODES) return;
    float4 xr[16];
    const float4* xp = (const float4*)(x + (size_t)r * 64);
#pragma unroll
    for (int j = 0; j < 16; ++j) xr[j] = xp[j];
    const float* xf = (const float*)xr;

    float acc[7] = {0.f, 0.f, 0.f, 0.f, 0.f, 0.f, 0.f};
#pragma unroll
    for (int k = 0; k < 64; ++k) {
        float xv = xf[k];
#pragma unroll
        for (int j = 0; j < 7; ++j)
            acc[j] += xv * W[j * 64 + k];  // uniform -> s_load
    }
    float4* op = (float4*)(out + (size_t)r * 8);
    op[0] = make_float4(acc[0], acc[1], acc[2], acc[3]);
    op[1] = make_float4(acc[4], acc[5], acc[6], 0.f);
}

// ---------------- gather aggregation: bf16 table, fp32 accumulate ----------

// Lane map: slot = lane>>3 (8 edge slots), ch8 = lane&7 (uint4 = 8 bf16 ch).
// csr: nt load (true read-once stream). out (B): REGULAR stores — B is
// re-read 4x by the next linear, so it must stay cache-warm (round-14
// regression: nt stores here cost ~11 us).
__global__ __launch_bounds__(256) void gather64b(const int* __restrict__ off,
                                                 const unsigned short* __restrict__ csr_src,
                                                 const unsigned int* __restrict__ tb,
                                                 const float* __restrict__ b,
                                                 float* __restrict__ out,
                                                 int do_relu) {
    int node = blockIdx.x * 4 + (threadIdx.x >> 6);
    if (node >= N_NODES) return;
    const int lane = threadIdx.x & 63;
    const int slot = lane >> 3;
    const int ch8  = lane & 7;
    int e0 = off[node], e1 = off[node + 1];
    const uint4* t4 = (const uint4*)tb;
    float s[8] = {0.f, 0.f, 0.f, 0.f, 0.f, 0.f, 0.f, 0.f};
    for (int e = e0; e < e1; e += 16) {
        int i0 = e + slot;
        int i1 = e + 8 + slot;
        bool p0 = i0 < e1, p1 = i1 < e1;
        unsigned int a0 = __builtin_nontemporal_load(csr_src + (p0 ? i0 : e));
        unsigned int a1 = __builtin_nontemporal_load(csr_src + (p1 ? i1 : e));
        uint4 v0 = t4[(size_t)a0 * 8 + ch8];
        uint4 v1 = t4[(size_t)a1 * 8 + ch8];
        if (p0) {
            s[0] += __uint_as_float(v0.x << 16);
            s[1] += __uint_as_float(v0.x & 0xFFFF0000u);
            s[2] += __uint_as_float(v0.y << 16);
            s[3] += __uint_as_float(v0.y & 0xFFFF0000u);
            s[4] += __uint_as_float(v0.z << 16);
            s[5] += __uint_as_float(v0.z & 0xFFFF0000u);
            s[6] += __uint_as_float(v0.w << 16);
            s[7] += __uint_as_float(v0.w & 0xFFFF0000u);
        }
        if (p1) {
            s[0] += __uint_as_float(v1.x << 16);
            s[1] += __uint_as_float(v1.x & 0xFFFF0000u);
            s[2] += __uint_as_float(v1.y << 16);
            s[3] += __uint_as_float(v1.y & 0xFFFF0000u);
            s[4] += __uint_as_float(v1.z << 16);
            s[5] += __uint_as_float(v1.z & 0xFFFF0000u);
            s[6] += __uint_as_float(v1.w << 16);
            s[7] += __uint_as_float(v1.w & 0xFFFF0000u);
        }
    }
#pragma unroll
    for (int d = 8; d <= 32; d <<= 1) {
#pragma unroll
        for (int j = 0; j < 8; ++j) s[j] += __shfl_xor(s[j], d, 64);
    }
    if (lane < 8) {
        const float4 b0 = ((const float4*)b)[ch8 * 2];
        const float4 b1 = ((const float4*)b)[ch8 * 2 + 1];
        float4 r0, r1;
        r0.x = s[0] + b0.x; r0.y = s[1] + b0.y; r0.z = s[2] + b0.z; r0.w = s[3] + b0.w;
        r1.x = s[4] + b1.x; r1.y = s[5] + b1.y; r1.z = s[6] + b1.z; r1.w = s[7] + b1.w;
        if (do_relu) {
            r0.x = fmaxf(r0.x, 0.f); r0.y = fmaxf(r0.y, 0.f);
            r0.z = fmaxf(r0.z, 0.f); r0.w = fmaxf(r0.w, 0.f);
            r1.x = fmaxf(r1.x, 0.f); r1.y = fmaxf(r1.y, 0.f);
            r1.z = fmaxf(r1.z, 0.f); r1.w = fmaxf(r1.w, 0.f);
        }
        float4* orow = (float4*)(out + (size_t)node * 64 + ch8 * 8);
        orow[0] = r0;
        orow[1] = r1;
    }
}

// 7-ch gather + bias + log_softmax (fp32 t3). slot = lane>>1, h = lane&1.
__global__ __launch_bounds__(256) void gather7_lsm(const int* __restrict__ off,
                                                   const unsigned short* __restrict__ csr_src,
                                                   const float* __restrict__ t3,
                                                   const float* __restrict__ b,
                                                   float* __restrict__ out) {
    int node = blockIdx.x * 4 + (threadIdx.x >> 6);
    if (node >= N_NODES) return;
    const int lane = threadIdx.x & 63;
    const int slot = lane >> 1;
    const int h    = lane & 1;
    int e0 = off[node], e1 = off[node + 1];
    const float4* t4 = (const float4*)t3;
    float sx = 0.f, sy = 0.f, sz = 0.f, sw = 0.f;
    for (int e = e0 + slot; e < e1; e += 32) {
        unsigned int s = __builtin_nontemporal_load(csr_src + e);
        float4 v = t4[(size_t)s * 2 + h];
        sx += v.x; sy += v.y; sz += v.z; sw += v.w;
    }
#pragma unroll
    for (int d = 2; d <= 32; d <<= 1) {
        sx += __shfl_xor(sx, d, 64); sy += __shfl_xor(sy, d, 64);
        sz += __shfl_xor(sz, d, 64); sw += __shfl_xor(sw, d, 64);
    }
    float z0 = sx + b[h * 4 + 0];
    float z1 = sy + b[h * 4 + 1];
    float z2 = sz + b[h * 4 + 2];
    float z3 = (h == 0) ? (sw + b[3]) : -1e30f;
    float m = fmaxf(fmaxf(z0, z1), fmaxf(z2, z3));
    m = fmaxf(m, __shfl_xor(m, 1, 64));
    float ex = __expf(z0 - m) + __expf(z1 - m) + __expf(z2 - m) + __expf(z3 - m);
    ex += __shfl_xor(ex, 1, 64);
    float l = m + __logf(ex);
    if (lane < 2) {
        float* o = out + (size_t)node * 7 + h * 4;
        o[0] = z0 - l; o[1] = z1 - l; o[2] = z2 - l;
        if (h == 0) o[3] = z3 - l;
    }
}

extern "C" void kernel_launch(void* const* d_in, const int* in_sizes, int n_in,
                              void* d_out, int out_size, void* d_ws, size_t ws_size,
                              hipStream_t stream) {
    const float* x  = (const float*)d_in[0];
    const int*   ei = (const int*)d_in[1];
    const float* W1 = (const float*)d_in[2];
    const float* b1 = (const float*)d_in[3];
    const float* W2 = (const float*)d_in[4];
    const float* b2 = (const float*)d_in[5];
    const float* W3 = (const float*)d_in[6];
    const float* b3 = (const float*)d_in[7];
    float* out = (float*)d_out;

    const int* src = ei;
    const int* dst = ei + N_EDGES;

    // workspace: A region (12.8 MB): phase-1 buckets (8.03 MB, dead after
    // build_csr) -> bf16 table (6.4 MB, layers 1-2) -> fp32 stride-8 t3.
    float* A = (float*)d_ws;                       // 12.8 MB
    float* B = A + (size_t)N_NODES * C;            // 12.8 MB (fp32 h buffer)
    unsigned short* csr = (unsigned short*)(B + (size_t)N_NODES * C);  // 3.2 MB
    int* off     = (int*)(csr + N_EDGES);          // 50001
    int* gcursor = off + N_NODES + 8;              // 196
    unsigned int* buckets = (unsigned int*)A;      // aliases A
    unsigned int* Abf     = (unsigned int*)A;      // bf16 table view

    const int l64grid = ((N_NODES + 255) / 256) * 4;  // 196 rowgroups x 4 cgs
    const int l7grid  = (N_NODES + 127) / 128;        // 391
    const int ngrid   = (N_NODES + 3) / 4;            // 12500

    // ---- CSR build
    (void)hipMemsetAsync(gcursor, 0, NB * sizeof(int), stream);
    bin_kernel<<<(N_EDGES + CHUNK - 1) / CHUNK, 256, 0, stream>>>(src, dst, buckets, gcursor);
    build_csr<<<NB, 256, 0, stream>>>(buckets, gcursor, csr, off);

    // ---- layer 1 (A free after build_csr)
    linear64_bf16<<<l64grid, 256, 0, stream>>>(x, W1, Abf);
    gather64b<<<ngrid, 256, 0, stream>>>(off, csr, Abf, b1, B, 1);

    // ---- layer 2
    linear64_bf16<<<l64grid, 256, 0, stream>>>(B, W2, Abf);
    gather64b<<<ngrid, 256, 0, stream>>>(off, csr, Abf, b2, B, 1);

    // ---- layer 3 (fp32 staging, stride-8)
    linear7_rows<<<l7grid, 128, 0, stream>>>(B, W3, A);
    gather7_lsm<<<ngrid, 256, 0, stream>>>(off, csr, A, b3, out);
}

// Round 16
// 261.741 us; speedup vs baseline: 1.1458x; 1.0498x over previous
//
#include <hip/hip_runtime.h>
#include <math.h>

#define N_NODES 50000
#define N_EDGES 1600000
#define C 64
#define OUTC 7

#define NB 196         // coarse buckets: dst >> 8  (49999>>8 = 195)
#define BCAP 10240     // bucket capacity (mean 8192, sigma ~90)
#define CHUNK 4096     // edges per phase-1 workgroup

// fp32 -> bf16 (RNE), packed pair into u32 (lo = even channel, hi = odd)
__device__ __forceinline__ unsigned int pk_bf16(float a, float b) {
    unsigned int ua = __float_as_uint(a);
    ua = (ua + 0x7FFFu + ((ua >> 16) & 1u)) >> 16;
    unsigned int ub = __float_as_uint(b);
    ub = (ub + 0x7FFFu + ((ub >> 16) & 1u)) >> 16;
    return ua | (ub << 16);
}

// ---------------- CSR build, phase 1: coarse binning ----------------
// Pack edge as (dst<<16)|src (both < 65536). bucket = v >> 24 (= dst>>8).
__global__ __launch_bounds__(256) void bin_kernel(const int* __restrict__ src,
                                                  const int* __restrict__ dst,
                                                  unsigned int* __restrict__ buckets,
                                                  int* __restrict__ gcursor) {
    __shared__ unsigned int staged[CHUNK];          // 16 KB
    __shared__ int hist[NB], scanb[NB], cur[NB], baseb[NB];
    const int tid = threadIdx.x;
    const int base = blockIdx.x * CHUNK;
    int n = N_EDGES - base; if (n > CHUNK) n = CHUNK;  // multiple of 4

    for (int b = tid; b < NB; b += 256) { hist[b] = 0; cur[b] = 0; }
    __syncthreads();

    const int4* src4 = (const int4*)(src + base);
    const int4* dst4 = (const int4*)(dst + base);
    unsigned int v[16];
    int nv = n >> 2;
#pragma unroll
    for (int k = 0; k < 4; ++k) {
        int i4 = k * 256 + tid;
        if (i4 < nv) {
            int4 s4 = src4[i4];
            int4 d4 = dst4[i4];
            unsigned int d0 = (unsigned int)d4.x, d1 = (unsigned int)d4.y;
            unsigned int d2 = (unsigned int)d4.z, d3 = (unsigned int)d4.w;
            v[k * 4 + 0] = (d0 << 16) | (unsigned int)s4.x;
            v[k * 4 + 1] = (d1 << 16) | (unsigned int)s4.y;
            v[k * 4 + 2] = (d2 << 16) | (unsigned int)s4.z;
            v[k * 4 + 3] = (d3 << 16) | (unsigned int)s4.w;
            atomicAdd(&hist[d0 >> 8], 1);
            atomicAdd(&hist[d1 >> 8], 1);
            atomicAdd(&hist[d2 >> 8], 1);
            atomicAdd(&hist[d3 >> 8], 1);
        }
    }
    __syncthreads();
    if (tid == 0) {
        int run = 0;
        for (int b = 0; b < NB; ++b) { scanb[b] = run; run += hist[b]; }
    }
    __syncthreads();
#pragma unroll
    for (int k = 0; k < 4; ++k) {
        int i4 = k * 256 + tid;
        if (i4 < nv) {
#pragma unroll
            for (int q = 0; q < 4; ++q) {
                unsigned int w = v[k * 4 + q];
                int b = w >> 24;
                int p = scanb[b] + atomicAdd(&cur[b], 1);
                staged[p] = w;
            }
        }
    }
    __syncthreads();
    if (tid < NB) baseb[tid] = atomicAdd(&gcursor[tid], hist[tid]);
    __syncthreads();
    for (int i = tid; i < n; i += 256) {
        unsigned int w = staged[i];
        int b = w >> 24;
        buckets[(size_t)b * BCAP + baseb[b] + (i - scanb[b])] = w;
    }
}

// ---------------- CSR build, phase 2: per-bucket local CSR ----------------
__global__ __launch_bounds__(256) void build_csr(const unsigned int* __restrict__ buckets,
                                                 const int* __restrict__ gcursor,
                                                 unsigned int* __restrict__ csr,
                                                 int* __restrict__ off) {
    __shared__ int hist[256], part[256], offx[256], cur[256];
    __shared__ int gl[NB];
    __shared__ int s_cnt, s_base;
    const int tid = threadIdx.x;
    const int b = blockIdx.x;

    hist[tid] = 0;
    cur[tid] = 0;
    if (tid < NB) gl[tid] = gcursor[tid];
    __syncthreads();
    if (tid == 0) {
        int bs = 0;
        for (int i = 0; i < b; ++i) bs += gl[i];
        s_base = bs;
        s_cnt = gl[b];
    }
    __syncthreads();
    const int cnt = s_cnt;
    const int gbase = s_base;
    const unsigned int* bk = buckets + (size_t)b * BCAP;

    for (int i = tid; i < cnt; i += 256) {
        atomicAdd(&hist[(bk[i] >> 16) & 255], 1);
    }
    __syncthreads();
    part[tid] = hist[tid];
    __syncthreads();
    for (int d = 1; d < 256; d <<= 1) {
        int t = (tid >= d) ? part[tid - d] : 0;
        __syncthreads();
        part[tid] += t;
        __syncthreads();
    }
    offx[tid] = (tid == 0) ? 0 : part[tid - 1];
    __syncthreads();
    int node = b * 256 + tid;
    if (node < N_NODES) off[node] = gbase + offx[tid];
    if (b == NB - 1 && tid == 0) off[N_NODES] = gbase + cnt;
    for (int i = tid; i < cnt; i += 256) {
        unsigned int w = bk[i];
        int dl = (w >> 16) & 255;
        int p = offx[dl] + atomicAdd(&cur[dl], 1);
        csr[gbase + p] = w & 0xFFFFu;
    }
}

// ---------------- dense linears ----------------

// Layer 1: fp32 x in, bf16 t out. Block-level cg split (cg = blockIdx&3,
// SGPR-native) -> W GEP stays provenance-clean -> s_load (K$).
__global__ __launch_bounds__(256) void linear64_x(const float* __restrict__ x,
                                                  const float* __restrict__ W,
                                                  unsigned int* __restrict__ tb) {
    const int cg = blockIdx.x & 3;
    const int r = (blockIdx.x >> 2) * 256 + threadIdx.x;
    if (r >= N_NODES) return;
    float4 xr[16];
    const float4* xp = (const float4*)(x + (size_t)r * 64);
#pragma unroll
    for (int j = 0; j < 16; ++j) xr[j] = xp[j];
    const float* xf = (const float*)xr;

    const float* Wp = W + cg * 16 * 64;   // uniform GEP -> s_load
    unsigned int* orow = tb + (size_t)r * 32 + cg * 8;
    for (int c0 = 0; c0 < 16; c0 += 8) {
        float acc[8] = {0.f, 0.f, 0.f, 0.f, 0.f, 0.f, 0.f, 0.f};
#pragma unroll
        for (int k = 0; k < 64; ++k) {
            float xv = xf[k];
#pragma unroll
            for (int j = 0; j < 8; ++j)
                acc[j] += xv * Wp[(c0 + j) * 64 + k];  // uniform -> s_load
        }
        uint4 w;
        w.x = pk_bf16(acc[0], acc[1]);
        w.y = pk_bf16(acc[2], acc[3]);
        w.z = pk_bf16(acc[4], acc[5]);
        w.w = pk_bf16(acc[6], acc[7]);
        ((uint4*)orow)[c0 >> 3] = w;
    }
}

// Layer 2: bf16 h in (packed u32 pairs), bf16 t out. Same cg split.
__global__ __launch_bounds__(256) void linear64_h(const unsigned int* __restrict__ hb,
                                                  const float* __restrict__ W,
                                                  unsigned int* __restrict__ tb) {
    const int cg = blockIdx.x & 3;
    const int r = (blockIdx.x >> 2) * 256 + threadIdx.x;
    if (r >= N_NODES) return;
    float xf[64];
    const uint4* hp = (const uint4*)(hb + (size_t)r * 32);
#pragma unroll
    for (int j = 0; j < 8; ++j) {
        uint4 u = hp[j];
        xf[j * 8 + 0] = __uint_as_float(u.x << 16);
        xf[j * 8 + 1] = __uint_as_float(u.x & 0xFFFF0000u);
        xf[j * 8 + 2] = __uint_as_float(u.y << 16);
        xf[j * 8 + 3] = __uint_as_float(u.y & 0xFFFF0000u);
        xf[j * 8 + 4] = __uint_as_float(u.z << 16);
        xf[j * 8 + 5] = __uint_as_float(u.z & 0xFFFF0000u);
        xf[j * 8 + 6] = __uint_as_float(u.w << 16);
        xf[j * 8 + 7] = __uint_as_float(u.w & 0xFFFF0000u);
    }

    const float* Wp = W + cg * 16 * 64;
    unsigned int* orow = tb + (size_t)r * 32 + cg * 8;
    for (int c0 = 0; c0 < 16; c0 += 8) {
        float acc[8] = {0.f, 0.f, 0.f, 0.f, 0.f, 0.f, 0.f, 0.f};
#pragma unroll
        for (int k = 0; k < 64; ++k) {
            float xv = xf[k];
#pragma unroll
            for (int j = 0; j < 8; ++j)
                acc[j] += xv * Wp[(c0 + j) * 64 + k];  // uniform -> s_load
        }
        uint4 w;
        w.x = pk_bf16(acc[0], acc[1]);
        w.y = pk_bf16(acc[2], acc[3]);
        w.z = pk_bf16(acc[4], acc[5]);
        w.w = pk_bf16(acc[6], acc[7]);
        ((uint4*)orow)[c0 >> 3] = w;
    }
}

// Layer 3: bf16 h in, fp32 stride-8 t3 out. Thread-per-row, W3 K$-resident.
__global__ __launch_bounds__(128) void linear7_h(const unsigned int* __restrict__ hb,
                                                 const float* __restrict__ W,
                                                 float* __restrict__ out) {
    int r = blockIdx.x * 128 + threadIdx.x;
    if (r >= N_NODES) return;
    float xf[64];
    const uint4* hp = (const uint4*)(hb + (size_t)r * 32);
#pragma unroll
    for (int j = 0; j < 8; ++j) {
        uint4 u = hp[j];
        xf[j * 8 + 0] = __uint_as_float(u.x << 16);
        xf[j * 8 + 1] = __uint_as_float(u.x & 0xFFFF0000u);
        xf[j * 8 + 2] = __uint_as_float(u.y << 16);
        xf[j * 8 + 3] = __uint_as_float(u.y & 0xFFFF0000u);
        xf[j * 8 + 4] = __uint_as_float(u.z << 16);
        xf[j * 8 + 5] = __uint_as_float(u.z & 0xFFFF0000u);
        xf[j * 8 + 6] = __uint_as_float(u.w << 16);
        xf[j * 8 + 7] = __uint_as_float(u.w & 0xFFFF0000u);
    }

    float acc[7] = {0.f, 0.f, 0.f, 0.f, 0.f, 0.f, 0.f};
#pragma unroll
    for (int k = 0; k < 64; ++k) {
        float xv = xf[k];
#pragma unroll
        for (int j = 0; j < 7; ++j)
            acc[j] += xv * W[j * 64 + k];  // uniform -> s_load
    }
    float4* op = (float4*)(out + (size_t)r * 8);
    op[0] = make_float4(acc[0], acc[1], acc[2], acc[3]);
    op[1] = make_float4(acc[4], acc[5], acc[6], 0.f);
}

// ---------------- gather aggregation: bf16 table -> bf16 h ----------------

// Lane map: slot = lane>>3 (8 edge slots), ch8 = lane&7 (uint4 = 8 bf16 ch).
// Regular (cached) csr loads — L1 line reuse matters (round-15 lesson).
// Output: packed bf16 h row (uint4 per lane, 128 B/node, coalesced).
__global__ __launch_bounds__(256) void gather64b(const int* __restrict__ off,
                                                 const unsigned int* __restrict__ csr_src,
                                                 const unsigned int* __restrict__ tb,
                                                 const float* __restrict__ b,
                                                 unsigned int* __restrict__ hb) {
    int node = blockIdx.x * 4 + (threadIdx.x >> 6);
    if (node >= N_NODES) return;
    const int lane = threadIdx.x & 63;
    const int slot = lane >> 3;
    const int ch8  = lane & 7;
    int e0 = off[node], e1 = off[node + 1];
    const uint4* t4 = (const uint4*)tb;
    float s[8] = {0.f, 0.f, 0.f, 0.f, 0.f, 0.f, 0.f, 0.f};
    for (int e = e0; e < e1; e += 16) {
        int i0 = e + slot;
        int i1 = e + 8 + slot;
        bool p0 = i0 < e1, p1 = i1 < e1;
        unsigned int a0 = csr_src[p0 ? i0 : e];
        unsigned int a1 = csr_src[p1 ? i1 : e];
        uint4 v0 = t4[(size_t)a0 * 8 + ch8];
        uint4 v1 = t4[(size_t)a1 * 8 + ch8];
        if (p0) {
            s[0] += __uint_as_float(v0.x << 16);
            s[1] += __uint_as_float(v0.x & 0xFFFF0000u);
            s[2] += __uint_as_float(v0.y << 16);
            s[3] += __uint_as_float(v0.y & 0xFFFF0000u);
            s[4] += __uint_as_float(v0.z << 16);
            s[5] += __uint_as_float(v0.z & 0xFFFF0000u);
            s[6] += __uint_as_float(v0.w << 16);
            s[7] += __uint_as_float(v0.w & 0xFFFF0000u);
        }
        if (p1) {
            s[0] += __uint_as_float(v1.x << 16);
            s[1] += __uint_as_float(v1.x & 0xFFFF0000u);
            s[2] += __uint_as_float(v1.y << 16);
            s[3] += __uint_as_float(v1.y & 0xFFFF0000u);
            s[4] += __uint_as_float(v1.z << 16);
            s[5] += __uint_as_float(v1.z & 0xFFFF0000u);
            s[6] += __uint_as_float(v1.w << 16);
            s[7] += __uint_as_float(v1.w & 0xFFFF0000u);
        }
    }
#pragma unroll
    for (int d = 8; d <= 32; d <<= 1) {
#pragma unroll
        for (int j = 0; j < 8; ++j) s[j] += __shfl_xor(s[j], d, 64);
    }
    if (lane < 8) {
        const float4 b0 = ((const float4*)b)[ch8 * 2];
        const float4 b1 = ((const float4*)b)[ch8 * 2 + 1];
        float r0 = fmaxf(s[0] + b0.x, 0.f);
        float r1 = fmaxf(s[1] + b0.y, 0.f);
        float r2 = fmaxf(s[2] + b0.z, 0.f);
        float r3 = fmaxf(s[3] + b0.w, 0.f);
        float r4 = fmaxf(s[4] + b1.x, 0.f);
        float r5 = fmaxf(s[5] + b1.y, 0.f);
        float r6 = fmaxf(s[6] + b1.z, 0.f);
        float r7 = fmaxf(s[7] + b1.w, 0.f);
        uint4 w;
        w.x = pk_bf16(r0, r1);
        w.y = pk_bf16(r2, r3);
        w.z = pk_bf16(r4, r5);
        w.w = pk_bf16(r6, r7);
        ((uint4*)(hb + (size_t)node * 32))[ch8] = w;
    }
}

// 7-ch gather + bias + log_softmax (fp32 t3). slot = lane>>1, h = lane&1.
__global__ __launch_bounds__(256) void gather7_lsm(const int* __restrict__ off,
                                                   const unsigned int* __restrict__ csr_src,
                                                   const float* __restrict__ t3,
                                                   const float* __restrict__ b,
                                                   float* __restrict__ out) {
    int node = blockIdx.x * 4 + (threadIdx.x >> 6);
    if (node >= N_NODES) return;
    const int lane = threadIdx.x & 63;
    const int slot = lane >> 1;
    const int h    = lane & 1;
    int e0 = off[node], e1 = off[node + 1];
    const float4* t4 = (const float4*)t3;
    float sx = 0.f, sy = 0.f, sz = 0.f, sw = 0.f;
    for (int e = e0 + slot; e < e1; e += 32) {
        unsigned int s = csr_src[e];
        float4 v = t4[(size_t)s * 2 + h];
        sx += v.x; sy += v.y; sz += v.z; sw += v.w;
    }
#pragma unroll
    for (int d = 2; d <= 32; d <<= 1) {
        sx += __shfl_xor(sx, d, 64); sy += __shfl_xor(sy, d, 64);
        sz += __shfl_xor(sz, d, 64); sw += __shfl_xor(sw, d, 64);
    }
    float z0 = sx + b[h * 4 + 0];
    float z1 = sy + b[h * 4 + 1];
    float z2 = sz + b[h * 4 + 2];
    float z3 = (h == 0) ? (sw + b[3]) : -1e30f;
    float m = fmaxf(fmaxf(z0, z1), fmaxf(z2, z3));
    m = fmaxf(m, __shfl_xor(m, 1, 64));
    float ex = __expf(z0 - m) + __expf(z1 - m) + __expf(z2 - m) + __expf(z3 - m);
    ex += __shfl_xor(ex, 1, 64);
    float l = m + __logf(ex);
    if (lane < 2) {
        float* o = out + (size_t)node * 7 + h * 4;
        o[0] = z0 - l; o[1] = z1 - l; o[2] = z2 - l;
        if (h == 0) o[3] = z3 - l;
    }
}

extern "C" void kernel_launch(void* const* d_in, const int* in_sizes, int n_in,
                              void* d_out, int out_size, void* d_ws, size_t ws_size,
                              hipStream_t stream) {
    const float* x  = (const float*)d_in[0];
    const int*   ei = (const int*)d_in[1];
    const float* W1 = (const float*)d_in[2];
    const float* b1 = (const float*)d_in[3];
    const float* W2 = (const float*)d_in[4];
    const float* b2 = (const float*)d_in[5];
    const float* W3 = (const float*)d_in[6];
    const float* b3 = (const float*)d_in[7];
    float* out = (float*)d_out;

    const int* src = ei;
    const int* dst = ei + N_EDGES;

    // workspace: A region (12.8 MB): phase-1 buckets (8.03 MB, dead after
    // build_csr) -> bf16 t table (6.4 MB) -> fp32 stride-8 t3 (1.6 MB).
    // B region holds the packed bf16 h table (6.4 MB).
    float* A = (float*)d_ws;                       // 12.8 MB
    float* B = A + (size_t)N_NODES * C;            // 12.8 MB
    unsigned int* csr = (unsigned int*)(B + (size_t)N_NODES * C);  // 6.4 MB u32
    int* off     = (int*)(csr + N_EDGES);          // 50001
    int* gcursor = off + N_NODES + 8;              // 196
    unsigned int* buckets = (unsigned int*)A;      // aliases A
    unsigned int* Abf     = (unsigned int*)A;      // bf16 t-table view
    unsigned int* Hbf     = (unsigned int*)B;      // bf16 h-table view

    const int l64grid = ((N_NODES + 255) / 256) * 4;  // 196 rowgroups x 4 cgs
    const int l7grid  = (N_NODES + 127) / 128;        // 391
    const int ngrid   = (N_NODES + 3) / 4;            // 12500

    // ---- CSR build
    (void)hipMemsetAsync(gcursor, 0, NB * sizeof(int), stream);
    bin_kernel<<<(N_EDGES + CHUNK - 1) / CHUNK, 256, 0, stream>>>(src, dst, buckets, gcursor);
    build_csr<<<NB, 256, 0, stream>>>(buckets, gcursor, csr, off);

    // ---- layer 1 (A free after build_csr)
    linear64_x<<<l64grid, 256, 0, stream>>>(x, W1, Abf);
    gather64b<<<ngrid, 256, 0, stream>>>(off, csr, Abf, b1, Hbf);

    // ---- layer 2
    linear64_h<<<l64grid, 256, 0, stream>>>(Hbf, W2, Abf);
    gather64b<<<ngrid, 256, 0, stream>>>(off, csr, Abf, b2, Hbf);

    // ---- layer 3 (fp32 t3, stride-8, written into A after t dead)
    linear7_h<<<l7grid, 128, 0, stream>>>(Hbf, W3, A);
    gather7_lsm<<<ngrid, 256, 0, stream>>>(off, csr, A, b3, out);
}

// Round 17
// 258.643 us; speedup vs baseline: 1.1595x; 1.0120x over previous
//
#include <hip/hip_runtime.h>
#include <math.h>

#define N_NODES 50000
#define N_EDGES 1600000
#define C 64
#define OUTC 7

#define NB 196         // coarse buckets: dst >> 8  (49999>>8 = 195)
#define BCAP 10240     // bucket capacity (mean 8192, sigma ~90)
#define CHUNK 8192     // edges per phase-1 workgroup (196 blocks = 1/CU)

// fp32 -> bf16 (RNE), packed pair into u32 (lo = even channel, hi = odd)
__device__ __forceinline__ unsigned int pk_bf16(float a, float b) {
    unsigned int ua = __float_as_uint(a);
    ua = (ua + 0x7FFFu + ((ua >> 16) & 1u)) >> 16;
    unsigned int ub = __float_as_uint(b);
    ub = (ub + 0x7FFFu + ((ub >> 16) & 1u)) >> 16;
    return ua | (ub << 16);
}

// ---------------- CSR build, phase 1: coarse binning ----------------
// Pack edge as (dst<<16)|src (both < 65536). bucket = v >> 24 (= dst>>8).
__global__ __launch_bounds__(256) void bin_kernel(const int* __restrict__ src,
                                                  const int* __restrict__ dst,
                                                  unsigned int* __restrict__ buckets,
                                                  int* __restrict__ gcursor) {
    __shared__ unsigned int staged[CHUNK];          // 32 KB
    __shared__ int hist[NB], scanb[NB], cur[NB], baseb[NB];
    const int tid = threadIdx.x;
    const int base = blockIdx.x * CHUNK;
    int n = N_EDGES - base; if (n > CHUNK) n = CHUNK;  // multiple of 4

    for (int b = tid; b < NB; b += 256) { hist[b] = 0; cur[b] = 0; }
    __syncthreads();

    const int4* src4 = (const int4*)(src + base);
    const int4* dst4 = (const int4*)(dst + base);
    unsigned int v[32];
    int nv = n >> 2;
#pragma unroll
    for (int k = 0; k < 8; ++k) {
        int i4 = k * 256 + tid;
        if (i4 < nv) {
            int4 s4 = src4[i4];
            int4 d4 = dst4[i4];
            unsigned int d0 = (unsigned int)d4.x, d1 = (unsigned int)d4.y;
            unsigned int d2 = (unsigned int)d4.z, d3 = (unsigned int)d4.w;
            v[k * 4 + 0] = (d0 << 16) | (unsigned int)s4.x;
            v[k * 4 + 1] = (d1 << 16) | (unsigned int)s4.y;
            v[k * 4 + 2] = (d2 << 16) | (unsigned int)s4.z;
            v[k * 4 + 3] = (d3 << 16) | (unsigned int)s4.w;
            atomicAdd(&hist[d0 >> 8], 1);
            atomicAdd(&hist[d1 >> 8], 1);
            atomicAdd(&hist[d2 >> 8], 1);
            atomicAdd(&hist[d3 >> 8], 1);
        }
    }
    __syncthreads();
    if (tid == 0) {
        int run = 0;
        for (int b = 0; b < NB; ++b) { scanb[b] = run; run += hist[b]; }
    }
    __syncthreads();
#pragma unroll
    for (int k = 0; k < 8; ++k) {
        int i4 = k * 256 + tid;
        if (i4 < nv) {
#pragma unroll
            for (int q = 0; q < 4; ++q) {
                unsigned int w = v[k * 4 + q];
                int b = w >> 24;
                int p = scanb[b] + atomicAdd(&cur[b], 1);
                staged[p] = w;
            }
        }
    }
    __syncthreads();
    if (tid < NB) baseb[tid] = atomicAdd(&gcursor[tid], hist[tid]);
    __syncthreads();
    for (int i = tid; i < n; i += 256) {
        unsigned int w = staged[i];
        int b = w >> 24;
        buckets[(size_t)b * BCAP + baseb[b] + (i - scanb[b])] = w;
    }
}

// ---------------- CSR build, phase 2: per-bucket local CSR ----------------
__global__ __launch_bounds__(256) void build_csr(const unsigned int* __restrict__ buckets,
                                                 const int* __restrict__ gcursor,
                                                 unsigned int* __restrict__ csr,
                                                 int* __restrict__ off) {
    __shared__ int hist[256], part[256], offx[256], cur[256];
    __shared__ int gl[NB];
    __shared__ int s_cnt, s_base;
    const int tid = threadIdx.x;
    const int b = blockIdx.x;

    hist[tid] = 0;
    cur[tid] = 0;
    if (tid < NB) gl[tid] = gcursor[tid];
    __syncthreads();
    if (tid == 0) {
        int bs = 0;
        for (int i = 0; i < b; ++i) bs += gl[i];
        s_base = bs;
        s_cnt = gl[b];
    }
    __syncthreads();
    const int cnt = s_cnt;
    const int gbase = s_base;
    const unsigned int* bk = buckets + (size_t)b * BCAP;

    for (int i = tid; i < cnt; i += 256) {
        atomicAdd(&hist[(bk[i] >> 16) & 255], 1);
    }
    __syncthreads();
    part[tid] = hist[tid];
    __syncthreads();
    for (int d = 1; d < 256; d <<= 1) {
        int t = (tid >= d) ? part[tid - d] : 0;
        __syncthreads();
        part[tid] += t;
        __syncthreads();
    }
    offx[tid] = (tid == 0) ? 0 : part[tid - 1];
    __syncthreads();
    int node = b * 256 + tid;
    if (node < N_NODES) off[node] = gbase + offx[tid];
    if (b == NB - 1 && tid == 0) off[N_NODES] = gbase + cnt;
    for (int i = tid; i < cnt; i += 256) {
        unsigned int w = bk[i];
        int dl = (w >> 16) & 255;
        int p = offx[dl] + atomicAdd(&cur[dl], 1);
        csr[gbase + p] = w & 0xFFFFu;
    }
}

// ---------------- dense linears ----------------

// Layer 1: fp32 x in, bf16 t out. Block-level cg split (cg = blockIdx&3,
// SGPR-native) -> W GEP stays provenance-clean -> s_load (K$).
__global__ __launch_bounds__(256) void linear64_x(const float* __restrict__ x,
                                                  const float* __restrict__ W,
                                                  unsigned int* __restrict__ tb) {
    const int cg = blockIdx.x & 3;
    const int r = (blockIdx.x >> 2) * 256 + threadIdx.x;
    if (r >= N_NODES) return;
    float4 xr[16];
    const float4* xp = (const float4*)(x + (size_t)r * 64);
#pragma unroll
    for (int j = 0; j < 16; ++j) xr[j] = xp[j];
    const float* xf = (const float*)xr;

    const float* Wp = W + cg * 16 * 64;   // uniform GEP -> s_load
    unsigned int* orow = tb + (size_t)r * 32 + cg * 8;
    for (int c0 = 0; c0 < 16; c0 += 8) {
        float acc[8] = {0.f, 0.f, 0.f, 0.f, 0.f, 0.f, 0.f, 0.f};
#pragma unroll
        for (int k = 0; k < 64; ++k) {
            float xv = xf[k];
#pragma unroll
            for (int j = 0; j < 8; ++j)
                acc[j] += xv * Wp[(c0 + j) * 64 + k];  // uniform -> s_load
        }
        uint4 w;
        w.x = pk_bf16(acc[0], acc[1]);
        w.y = pk_bf16(acc[2], acc[3]);
        w.z = pk_bf16(acc[4], acc[5]);
        w.w = pk_bf16(acc[6], acc[7]);
        ((uint4*)orow)[c0 >> 3] = w;
    }
}

// Layer 2: bf16 h in (packed u32 pairs), bf16 t out. Same cg split.
__global__ __launch_bounds__(256) void linear64_h(const unsigned int* __restrict__ hb,
                                                  const float* __restrict__ W,
                                                  unsigned int* __restrict__ tb) {
    const int cg = blockIdx.x & 3;
    const int r = (blockIdx.x >> 2) * 256 + threadIdx.x;
    if (r >= N_NODES) return;
    float xf[64];
    const uint4* hp = (const uint4*)(hb + (size_t)r * 32);
#pragma unroll
    for (int j = 0; j < 8; ++j) {
        uint4 u = hp[j];
        xf[j * 8 + 0] = __uint_as_float(u.x << 16);
        xf[j * 8 + 1] = __uint_as_float(u.x & 0xFFFF0000u);
        xf[j * 8 + 2] = __uint_as_float(u.y << 16);
        xf[j * 8 + 3] = __uint_as_float(u.y & 0xFFFF0000u);
        xf[j * 8 + 4] = __uint_as_float(u.z << 16);
        xf[j * 8 + 5] = __uint_as_float(u.z & 0xFFFF0000u);
        xf[j * 8 + 6] = __uint_as_float(u.w << 16);
        xf[j * 8 + 7] = __uint_as_float(u.w & 0xFFFF0000u);
    }

    const float* Wp = W + cg * 16 * 64;
    unsigned int* orow = tb + (size_t)r * 32 + cg * 8;
    for (int c0 = 0; c0 < 16; c0 += 8) {
        float acc[8] = {0.f, 0.f, 0.f, 0.f, 0.f, 0.f, 0.f, 0.f};
#pragma unroll
        for (int k = 0; k < 64; ++k) {
            float xv = xf[k];
#pragma unroll
            for (int j = 0; j < 8; ++j)
                acc[j] += xv * Wp[(c0 + j) * 64 + k];  // uniform -> s_load
        }
        uint4 w;
        w.x = pk_bf16(acc[0], acc[1]);
        w.y = pk_bf16(acc[2], acc[3]);
        w.z = pk_bf16(acc[4], acc[5]);
        w.w = pk_bf16(acc[6], acc[7]);
        ((uint4*)orow)[c0 >> 3] = w;
    }
}

// Layer 3: bf16 h in, fp32 stride-8 t3 out. Thread-per-row, W3 K$-resident.
__global__ __launch_bounds__(128) void linear7_h(const unsigned int* __restrict__ hb,
                                                 const float* __restrict__ W,
                                                 float* __restrict__ out) {
    int r = blockIdx.x * 128 + threadIdx.x;
    if (r >= N_NODES) return;
    float xf[64];
    const uint4* hp = (const uint4*)(hb + (size_t)r * 32);
#pragma unroll
    for (int j = 0; j < 8; ++j) {
        uint4 u = hp[j];
        xf[j * 8 + 0] = __uint_as_float(u.x << 16);
        xf[j * 8 + 1] = __uint_as_float(u.x & 0xFFFF0000u);
        xf[j * 8 + 2] = __uint_as_float(u.y << 16);
        xf[j * 8 + 3] = __uint_as_float(u.y & 0xFFFF0000u);
        xf[j * 8 + 4] = __uint_as_float(u.z << 16);
        xf[j * 8 + 5] = __uint_as_float(u.z & 0xFFFF0000u);
        xf[j * 8 + 6] = __uint_as_float(u.w << 16);
        xf[j * 8 + 7] = __uint_as_float(u.w & 0xFFFF0000u);
    }

    float acc[7] = {0.f, 0.f, 0.f, 0.f, 0.f, 0.f, 0.f};
#pragma unroll
    for (int k = 0; k < 64; ++k) {
        float xv = xf[k];
#pragma unroll
        for (int j = 0; j < 7; ++j)
            acc[j] += xv * W[j * 64 + k];  // uniform -> s_load
    }
    float4* op = (float4*)(out + (size_t)r * 8);
    op[0] = make_float4(acc[0], acc[1], acc[2], acc[3]);
    op[1] = make_float4(acc[4], acc[5], acc[6], 0.f);
}

// ---------------- gather aggregation: bf16 table -> bf16 h ----------------

// Lane map: slot = lane>>3 (8 edge slots), ch8 = lane&7 (uint4 = 8 bf16 ch).
// Regular (cached) csr loads — L1 line reuse matters (round-15 lesson).
// Output: packed bf16 h row (uint4 per lane, 128 B/node, coalesced).
__global__ __launch_bounds__(256) void gather64b(const int* __restrict__ off,
                                                 const unsigned int* __restrict__ csr_src,
                                                 const unsigned int* __restrict__ tb,
                                                 const float* __restrict__ b,
                                                 unsigned int* __restrict__ hb) {
    int node = blockIdx.x * 4 + (threadIdx.x >> 6);
    if (node >= N_NODES) return;
    const int lane = threadIdx.x & 63;
    const int slot = lane >> 3;
    const int ch8  = lane & 7;
    int e0 = off[node], e1 = off[node + 1];
    const uint4* t4 = (const uint4*)tb;
    float s[8] = {0.f, 0.f, 0.f, 0.f, 0.f, 0.f, 0.f, 0.f};
    for (int e = e0; e < e1; e += 16) {
        int i0 = e + slot;
        int i1 = e + 8 + slot;
        bool p0 = i0 < e1, p1 = i1 < e1;
        unsigned int a0 = csr_src[p0 ? i0 : e];
        unsigned int a1 = csr_src[p1 ? i1 : e];
        uint4 v0 = t4[(size_t)a0 * 8 + ch8];
        uint4 v1 = t4[(size_t)a1 * 8 + ch8];
        if (p0) {
            s[0] += __uint_as_float(v0.x << 16);
            s[1] += __uint_as_float(v0.x & 0xFFFF0000u);
            s[2] += __uint_as_float(v0.y << 16);
            s[3] += __uint_as_float(v0.y & 0xFFFF0000u);
            s[4] += __uint_as_float(v0.z << 16);
            s[5] += __uint_as_float(v0.z & 0xFFFF0000u);
            s[6] += __uint_as_float(v0.w << 16);
            s[7] += __uint_as_float(v0.w & 0xFFFF0000u);
        }
        if (p1) {
            s[0] += __uint_as_float(v1.x << 16);
            s[1] += __uint_as_float(v1.x & 0xFFFF0000u);
            s[2] += __uint_as_float(v1.y << 16);
            s[3] += __uint_as_float(v1.y & 0xFFFF0000u);
            s[4] += __uint_as_float(v1.z << 16);
            s[5] += __uint_as_float(v1.z & 0xFFFF0000u);
            s[6] += __uint_as_float(v1.w << 16);
            s[7] += __uint_as_float(v1.w & 0xFFFF0000u);
        }
    }
#pragma unroll
    for (int d = 8; d <= 32; d <<= 1) {
#pragma unroll
        for (int j = 0; j < 8; ++j) s[j] += __shfl_xor(s[j], d, 64);
    }
    if (lane < 8) {
        const float4 b0 = ((const float4*)b)[ch8 * 2];
        const float4 b1 = ((const float4*)b)[ch8 * 2 + 1];
        float r0 = fmaxf(s[0] + b0.x, 0.f);
        float r1 = fmaxf(s[1] + b0.y, 0.f);
        float r2 = fmaxf(s[2] + b0.z, 0.f);
        float r3 = fmaxf(s[3] + b0.w, 0.f);
        float r4 = fmaxf(s[4] + b1.x, 0.f);
        float r5 = fmaxf(s[5] + b1.y, 0.f);
        float r6 = fmaxf(s[6] + b1.z, 0.f);
        float r7 = fmaxf(s[7] + b1.w, 0.f);
        uint4 w;
        w.x = pk_bf16(r0, r1);
        w.y = pk_bf16(r2, r3);
        w.z = pk_bf16(r4, r5);
        w.w = pk_bf16(r6, r7);
        ((uint4*)(hb + (size_t)node * 32))[ch8] = w;
    }
}

// 7-ch gather + bias + log_softmax (fp32 t3). slot = lane>>1, h = lane&1.
__global__ __launch_bounds__(256) void gather7_lsm(const int* __restrict__ off,
                                                   const unsigned int* __restrict__ csr_src,
                                                   const float* __restrict__ t3,
                                                   const float* __restrict__ b,
                                                   float* __restrict__ out) {
    int node = blockIdx.x * 4 + (threadIdx.x >> 6);
    if (node >= N_NODES) return;
    const int lane = threadIdx.x & 63;
    const int slot = lane >> 1;
    const int h    = lane & 1;
    int e0 = off[node], e1 = off[node + 1];
    const float4* t4 = (const float4*)t3;
    float sx = 0.f, sy = 0.f, sz = 0.f, sw = 0.f;
    for (int e = e0 + slot; e < e1; e += 32) {
        unsigned int s = csr_src[e];
        float4 v = t4[(size_t)s * 2 + h];
        sx += v.x; sy += v.y; sz += v.z; sw += v.w;
    }
#pragma unroll
    for (int d = 2; d <= 32; d <<= 1) {
        sx += __shfl_xor(sx, d, 64); sy += __shfl_xor(sy, d, 64);
        sz += __shfl_xor(sz, d, 64); sw += __shfl_xor(sw, d, 64);
    }
    float z0 = sx + b[h * 4 + 0];
    float z1 = sy + b[h * 4 + 1];
    float z2 = sz + b[h * 4 + 2];
    float z3 = (h == 0) ? (sw + b[3]) : -1e30f;
    float m = fmaxf(fmaxf(z0, z1), fmaxf(z2, z3));
    m = fmaxf(m, __shfl_xor(m, 1, 64));
    float ex = __expf(z0 - m) + __expf(z1 - m) + __expf(z2 - m) + __expf(z3 - m);
    ex += __shfl_xor(ex, 1, 64);
    float l = m + __logf(ex);
    if (lane < 2) {
        float* o = out + (size_t)node * 7 + h * 4;
        o[0] = z0 - l; o[1] = z1 - l; o[2] = z2 - l;
        if (h == 0) o[3] = z3 - l;
    }
}

extern "C" void kernel_launch(void* const* d_in, const int* in_sizes, int n_in,
                              void* d_out, int out_size, void* d_ws, size_t ws_size,
                              hipStream_t stream) {
    const float* x  = (const float*)d_in[0];
    const int*   ei = (const int*)d_in[1];
    const float* W1 = (const float*)d_in[2];
    const float* b1 = (const float*)d_in[3];
    const float* W2 = (const float*)d_in[4];
    const float* b2 = (const float*)d_in[5];
    const float* W3 = (const float*)d_in[6];
    const float* b3 = (const float*)d_in[7];
    float* out = (float*)d_out;

    const int* src = ei;
    const int* dst = ei + N_EDGES;

    // workspace: A region (12.8 MB): phase-1 buckets (8.03 MB, dead after
    // build_csr) -> bf16 t table (6.4 MB) -> fp32 stride-8 t3 (1.6 MB).
    // B region holds the packed bf16 h table (6.4 MB).
    float* A = (float*)d_ws;                       // 12.8 MB
    float* B = A + (size_t)N_NODES * C;            // 12.8 MB
    unsigned int* csr = (unsigned int*)(B + (size_t)N_NODES * C);  // 6.4 MB u32
    int* off     = (int*)(csr + N_EDGES);          // 50001
    int* gcursor = off + N_NODES + 8;              // 196
    unsigned int* buckets = (unsigned int*)A;      // aliases A
    unsigned int* Abf     = (unsigned int*)A;      // bf16 t-table view
    unsigned int* Hbf     = (unsigned int*)B;      // bf16 h-table view

    const int l64grid = ((N_NODES + 255) / 256) * 4;  // 196 rowgroups x 4 cgs
    const int l7grid  = (N_NODES + 127) / 128;        // 391
    const int ngrid   = (N_NODES + 3) / 4;            // 12500

    // ---- CSR build
    (void)hipMemsetAsync(gcursor, 0, NB * sizeof(int), stream);
    bin_kernel<<<(N_EDGES + CHUNK - 1) / CHUNK, 256, 0, stream>>>(src, dst, buckets, gcursor);
    build_csr<<<NB, 256, 0, stream>>>(buckets, gcursor, csr, off);

    // ---- layer 1 (A free after build_csr)
    linear64_x<<<l64grid, 256, 0, stream>>>(x, W1, Abf);
    gather64b<<<ngrid, 256, 0, stream>>>(off, csr, Abf, b1, Hbf);

    // ---- layer 2
    linear64_h<<<l64grid, 256, 0, stream>>>(Hbf, W2, Abf);
    gather64b<<<ngrid, 256, 0, stream>>>(off, csr, Abf, b2, Hbf);

    // ---- layer 3 (fp32 t3, stride-8, written into A after t dead)
    linear7_h<<<l7grid, 128, 0, stream>>>(Hbf, W3, A);
    gather7_lsm<<<ngrid, 256, 0, stream>>>(off, csr, A, b3, out);
}